// Round 3
// baseline (103.103 us; speedup 1.0000x reference)
//
#include <hip/hip_runtime.h>

typedef __attribute__((ext_vector_type(8))) short bf16x8;
typedef __attribute__((ext_vector_type(4))) float f32x4;

#define B_    2048
#define S_    512

// ws layout (bytes). Total 1.77 MB.
#define OFF_POOLED 0u          // 2048*128*2 = 524288   pooled bf16, K padded 100->128
#define OFF_WT1    524288u     // 512*128*2  = 131072   Wt1[n][k]
#define OFF_WT2    655360u     // 512*512*2  = 524288   Wt2[n][k]
#define OFF_WT3    1179648u    // 512*512*2  = 524288   Wt3[n][k]
#define OFF_WTF    1703936u    // 16*512*2   = 16384    Wtf[n][k], n<2 real
#define OFF_PREF   1720320u    // 512*64*4   = 131072   float pref[512][64] (50 used)

__device__ __forceinline__ unsigned short f2bf(float f) {
    unsigned int u = __float_as_uint(f);
    u += 0x7FFFu + ((u >> 16) & 1u);          // round-to-nearest-even
    return (unsigned short)(u >> 16);
}

#define MFMA16(a, b, c) __builtin_amdgcn_mfma_f32_16x16x32_bf16((a), (b), (c), 0, 0, 0)

// ---------------- convert: fp32 weights -> transposed/padded bf16 (tiled) ----
// 64x64 tile per block: coalesced fp32 read -> LDS -> coalesced bf16 write.
__global__ __launch_bounds__(256) void convert_kernel(
    const float* __restrict__ W1, const float* __restrict__ W2,
    const float* __restrict__ W3, const float* __restrict__ Wf,
    unsigned short* __restrict__ ws)
{
    __shared__ float tile[64][65];
    const int bid = blockIdx.x;
    const float* src; unsigned short* dst;
    int k0, n0, Ksrc, Nsrc, Kpad, Ndst;
    if (bid < 64)       { src = W2; dst = ws + OFF_WT2/2; k0 = (bid>>3)*64;       n0 = (bid&7)*64;       Ksrc = 512; Nsrc = 512; Kpad = 512; Ndst = 512; }
    else if (bid < 128) { int b = bid-64;  src = W3; dst = ws + OFF_WT3/2; k0 = (b>>3)*64; n0 = (b&7)*64; Ksrc = 512; Nsrc = 512; Kpad = 512; Ndst = 512; }
    else if (bid < 144) { int b = bid-128; src = W1; dst = ws + OFF_WT1/2; k0 = (b>>3)*64; n0 = (b&7)*64; Ksrc = 100; Nsrc = 512; Kpad = 128; Ndst = 512; }
    else                { int b = bid-144; src = Wf; dst = ws + OFF_WTF/2; k0 = b*64;      n0 = 0;        Ksrc = 512; Nsrc = 2;   Kpad = 512; Ndst = 16;  }

    const int c  = threadIdx.x & 63;
    const int r4 = threadIdx.x >> 6;
#pragma unroll
    for (int rr = 0; rr < 16; ++rr) {
        int r = rr*4 + r4;
        float v = 0.f;
        if (k0 + r < Ksrc && n0 + c < Nsrc) v = src[(size_t)(k0+r)*Nsrc + n0 + c];
        tile[r][c] = v;
    }
    __syncthreads();
#pragma unroll
    for (int rr = 0; rr < 16; ++rr) {
        int nrow = rr*4 + r4;                 // n index within tile
        if (n0 + nrow < Ndst)
            dst[(size_t)(n0+nrow)*Kpad + k0 + c] = f2bf(tile[c][nrow]);
    }
}

// ---------------- prep: inclusive prefix over pos_table[pos0[s]] rows --------
// pos rows are identical across batch (jnp.tile of arange); one block computes
// pref[s][d] = sum_{i<=s} pos_table[pos[0][i]][d] so pool does a single read.
__global__ __launch_bounds__(512) void prep_kernel(
    const float* __restrict__ post, const int* __restrict__ pos,
    float* __restrict__ pref)
{
    __shared__ int   idx_s[512];
    __shared__ float pl[512][52];
    const int tid = threadIdx.x, lane = tid & 63, wave = tid >> 6;
    idx_s[tid] = pos[tid];
    __syncthreads();
    if (lane < 50) {
        float run = 0.f;
        for (int i = 0; i < 64; ++i) {
            int s = wave*64 + i;
            run += post[(size_t)idx_s[s]*50 + lane];
            pl[s][lane] = run;
        }
    }
    __syncthreads();
    if (lane < 50) {
        float off = 0.f;
        for (int w = 0; w < wave; ++w) off += pl[w*64 + 63][lane];
        for (int i = 0; i < 64; ++i) {
            int s = wave*64 + i;
            pref[(size_t)s*64 + lane] = pl[s][lane] + off;
        }
    }
}

// ---------------- pool: emb gather + masked mean, writes bf16 [2048][128] ----
// Indices preloaded to LDS once; 16 independent gathers in flight per wave.
__global__ __launch_bounds__(256) void pool_kernel(
    const float* __restrict__ emb, const int* __restrict__ seq,
    const int* __restrict__ seqlen, const float* __restrict__ pref,
    unsigned short* __restrict__ pooled_p)
{
    const int b = blockIdx.x, tid = threadIdx.x;
    const int lane = tid & 63, wave = tid >> 6;
    const int L = seqlen[b];
    __shared__ int   idx_s[512];
    __shared__ float red[4][52];

    const int* seqrow = seq + (size_t)b * S_;
    idx_s[tid]       = seqrow[tid];
    idx_s[tid + 256] = seqrow[tid + 256];
    __syncthreads();

    float acc[4] = {0.f, 0.f, 0.f, 0.f};
    for (int base = wave * 16; base < L; base += 64) {
#pragma unroll
        for (int j = 0; j < 16; ++j) {              // static j -> regs, 16 loads in flight
            if (base + j < L) {
                int tok = idx_s[base + j];          // LDS broadcast, no shuffle dep
                if (lane < 50)
                    acc[j & 3] += emb[(size_t)tok * 50 + lane];
            }
        }
    }
    if (lane < 50) red[wave][lane] = (acc[0] + acc[1]) + (acc[2] + acc[3]);
    __syncthreads();

    if (tid < 128) {
        float v = 0.f;
        if (tid < 50)
            v = (red[0][tid] + red[1][tid] + red[2][tid] + red[3][tid]) / (float)L;
        else if (tid < 100)
            v = pref[(size_t)(L-1)*64 + (tid - 50)] / (float)L;
        pooled_p[(size_t)b * 128 + tid] = f2bf(v);
    }
}

// ---------------- fused bf16-MFMA MLP ----------------------------------------
// Block: 8 real rows (M padded to 16), 512 threads = 8 waves x 64-col panel.
// Activations ping-pong in swizzled LDS; B-frags prefetched to register arrays.
__device__ __forceinline__ void load_afrags(bf16x8 (&a)[16],
    const unsigned short* h, int row, int kq)
{
#pragma unroll
    for (int ks = 0; ks < 16; ++ks)
        a[ks] = *(const bf16x8*)((const char*)h +
                  (((unsigned)(row * 1024 + ks * 64 + kq * 16)) ^ ((row & 7) << 4)));
}

template<int KS>
__device__ __forceinline__ void layer_compute(
    const bf16x8 (&a)[KS], const unsigned short* __restrict__ Wt,
    const float* __restrict__ bias, unsigned short* hout,
    int wave, int row, int kq)
{
#pragma unroll
    for (int nt = 0; nt < 4; nt += 2) {
        const int c0 = wave * 64 + nt * 16 + row;
        const int c1 = c0 + 16;
        const unsigned short* p0 = Wt + (size_t)c0 * (KS * 32) + kq * 8;
        const unsigned short* p1 = Wt + (size_t)c1 * (KS * 32) + kq * 8;
        bf16x8 bv0[KS], bv1[KS];
#pragma unroll
        for (int ks = 0; ks < KS; ++ks) {           // all B loads issued first (ILP)
            bv0[ks] = *(const bf16x8*)(p0 + ks * 32);
            bv1[ks] = *(const bf16x8*)(p1 + ks * 32);
        }
        f32x4 acc0 = {0.f, 0.f, 0.f, 0.f};
        f32x4 acc1 = {0.f, 0.f, 0.f, 0.f};
#pragma unroll
        for (int ks = 0; ks < KS; ++ks) {
            acc0 = MFMA16(a[ks], bv0[ks], acc0);
            acc1 = MFMA16(a[ks], bv1[ks], acc1);
        }
        const float bb0 = bias[c0], bb1 = bias[c1];
#pragma unroll
        for (int r = 0; r < 4; ++r) {
            int hrow = kq * 4 + r;
            unsigned base = hrow * 1024;
            *(unsigned short*)((char*)hout + ((base + c0 * 2) ^ ((hrow & 7) << 4))) =
                f2bf(fmaxf(acc0[r] + bb0, 0.f));
            *(unsigned short*)((char*)hout + ((base + c1 * 2) ^ ((hrow & 7) << 4))) =
                f2bf(fmaxf(acc1[r] + bb1, 0.f));
        }
    }
}

__global__ __launch_bounds__(512, 2) void mlp_kernel(
    const unsigned short* __restrict__ ws_ro,
    const float* __restrict__ b1, const float* __restrict__ b2,
    const float* __restrict__ b3, const float* __restrict__ bfin,
    float* __restrict__ out)
{
    __shared__ unsigned short hA[8192];
    __shared__ unsigned short hB[8192];

    const int tid  = threadIdx.x;
    const int wave = tid >> 6;
    const int lane = tid & 63;
    const int row  = lane & 15;   // M-row (A/D) and N-col (B)
    const int kq   = lane >> 4;   // k-quarter
    const int b0   = blockIdx.x * 8;

    const unsigned short* pooled = ws_ro + OFF_POOLED / 2;
    const unsigned short* Wt1    = ws_ro + OFF_WT1 / 2;
    const unsigned short* Wt2    = ws_ro + OFF_WT2 / 2;
    const unsigned short* Wt3    = ws_ro + OFF_WT3 / 2;
    const unsigned short* Wtf    = ws_ro + OFF_WTF / 2;

    // ---- Layer 1 (K=128): A straight from global; rows 8..15 pad/garbage (inert)
    bf16x8 a1[4];
#pragma unroll
    for (int ks = 0; ks < 4; ++ks)
        a1[ks] = *(const bf16x8*)(pooled + (size_t)(b0 + row) * 128 + ks * 32 + kq * 8);
    layer_compute<4>(a1, Wt1, b1, hA, wave, row, kq);
    __syncthreads();

    // ---- Layer 2 (K=512): hA -> hB
    bf16x8 a[16];
    load_afrags(a, hA, row, kq);
    layer_compute<16>(a, Wt2, b2, hB, wave, row, kq);
    __syncthreads();

    // ---- Layer 3 (K=512): hB -> hA
    load_afrags(a, hB, row, kq);
    layer_compute<16>(a, Wt3, b3, hA, wave, row, kq);
    __syncthreads();

    // ---- Final (K=512, N padded 2->16): wave 0 only
    if (wave == 0) {
        load_afrags(a, hA, row, kq);
        f32x4 acc = {0.f, 0.f, 0.f, 0.f};
        const unsigned short* pw = Wtf + (size_t)row * 512 + kq * 8;
#pragma unroll
        for (int ks = 0; ks < 16; ++ks) {
            bf16x8 bv = *(const bf16x8*)(pw + ks * 32);
            acc = MFMA16(a[ks], bv, acc);
        }
        if (row < 2 && kq < 2) {
            float bb = bfin[row];
#pragma unroll
            for (int r = 0; r < 4; ++r) {
                int m = kq * 4 + r;                  // real rows 0..7
                out[(size_t)(b0 + m) * 2 + row] = acc[r] + bb;
            }
        }
    }
}

extern "C" void kernel_launch(void* const* d_in, const int* in_sizes, int n_in,
                              void* d_out, int out_size, void* d_ws, size_t ws_size,
                              hipStream_t stream)
{
    const float* emb    = (const float*)d_in[0];
    const float* post   = (const float*)d_in[1];
    const float* W1     = (const float*)d_in[2];
    const float* b1     = (const float*)d_in[3];
    const float* W2     = (const float*)d_in[4];
    const float* b2     = (const float*)d_in[5];
    const float* W3     = (const float*)d_in[6];
    const float* b3     = (const float*)d_in[7];
    const float* Wf     = (const float*)d_in[8];
    const float* bf     = (const float*)d_in[9];
    const int*   seq    = (const int*)d_in[10];
    const int*   seqlen = (const int*)d_in[11];
    const int*   pos    = (const int*)d_in[12];
    float*       out    = (float*)d_out;

    unsigned short* ws = (unsigned short*)d_ws;
    float* pref = (float*)((char*)d_ws + OFF_PREF);

    prep_kernel<<<1, 512, 0, stream>>>(post, pos, pref);
    convert_kernel<<<152, 256, 0, stream>>>(W1, W2, W3, Wf, ws);
    pool_kernel<<<B_, 256, 0, stream>>>(emb, seq, seqlen, pref,
                                        ws + OFF_POOLED / 2);
    mlp_kernel<<<B_ / 8, 512, 0, stream>>>(ws, b1, b2, b3, bf, out);
}

// Round 4
// 74.296 us; speedup vs baseline: 1.3877x; 1.3877x over previous
//
#include <hip/hip_runtime.h>

typedef __attribute__((ext_vector_type(8))) short bf16x8;
typedef __attribute__((ext_vector_type(4))) float f32x4;

#define B_    2048
#define S_    512

// ws layout (bytes)
#define OFF_WT1   0u          // 512*128*2  = 131072   Wt1[n][k] (transposed, k<100 real)
#define OFF_WT2   131072u     // 512*512*2  = 524288   Wt2[n][k]
#define OFF_WT3   655360u     // 512*512*2  = 524288   Wt3[n][k]
#define OFF_WTF   1179648u    // 16*512*2   = 16384    Wtf[n][k], n<2 real
#define OFF_PREF  1196032u    // 512*64*4   = 131072   float pref[512][64] (50 used)
#define OFF_EMBB  1327104u    // 50000*56*2 = 5600000  bf16 emb, padded 50->56 (16B rows)
#define WS_NEED_PAD 6927104u

__device__ __forceinline__ unsigned short f2bf(float f) {
    unsigned int u = __float_as_uint(f);
    u += 0x7FFFu + ((u >> 16) & 1u);          // round-to-nearest-even
    return (unsigned short)(u >> 16);
}

#define MFMA16(a, b, c) __builtin_amdgcn_mfma_f32_16x16x32_bf16((a), (b), (c), 0, 0, 0)

// ---------------- prep_convert: weights->bf16^T, pos-prefix, emb->bf16 -------
__global__ __launch_bounds__(256) void prep_convert(
    const float* __restrict__ W1, const float* __restrict__ W2,
    const float* __restrict__ W3, const float* __restrict__ Wf,
    const float* __restrict__ post, const int* __restrict__ pos,
    const float* __restrict__ emb,
    unsigned short* __restrict__ ws, float* __restrict__ pref, int do_emb)
{
    const int bid = blockIdx.x;
    const int tid = threadIdx.x;

    if (bid < 152) {                      // ---- weight transpose-convert
        __shared__ float tile[64][65];
        const float* src; unsigned short* dst;
        int k0, n0, Ksrc, Nsrc, Kpad, Ndst;
        if (bid < 64)       { src = W2; dst = ws + OFF_WT2/2; k0 = (bid>>3)*64;  n0 = (bid&7)*64;  Ksrc = 512; Nsrc = 512; Kpad = 512; Ndst = 512; }
        else if (bid < 128) { int b = bid-64;  src = W3; dst = ws + OFF_WT3/2; k0 = (b>>3)*64; n0 = (b&7)*64; Ksrc = 512; Nsrc = 512; Kpad = 512; Ndst = 512; }
        else if (bid < 144) { int b = bid-128; src = W1; dst = ws + OFF_WT1/2; k0 = (b>>3)*64; n0 = (b&7)*64; Ksrc = 100; Nsrc = 512; Kpad = 128; Ndst = 512; }
        else                { int b = bid-144; src = Wf; dst = ws + OFF_WTF/2; k0 = b*64;      n0 = 0;        Ksrc = 512; Nsrc = 2;   Kpad = 512; Ndst = 16;  }

        const int c  = tid & 63;
        const int r4 = tid >> 6;
#pragma unroll
        for (int rr = 0; rr < 16; ++rr) {
            int r = rr*4 + r4;
            float v = 0.f;
            if (k0 + r < Ksrc && n0 + c < Nsrc) v = src[(size_t)(k0+r)*Nsrc + n0 + c];
            tile[r][c] = v;
        }
        __syncthreads();
#pragma unroll
        for (int rr = 0; rr < 16; ++rr) {
            int nrow = rr*4 + r4;
            if (n0 + nrow < Ndst)
                dst[(size_t)(n0+nrow)*Kpad + k0 + c] = f2bf(tile[c][nrow]);
        }
    } else if (bid == 152) {              // ---- pos-prefix (parallel, 4 chunks)
        __shared__ int   idx_s[512];
        __shared__ float csum[4][52];
        idx_s[tid]       = pos[tid];
        idx_s[tid + 256] = pos[tid + 256];
        __syncthreads();
        const int c = tid >> 6, d = tid & 63;
        if (d < 50) {
            float run = 0.f;
            for (int s = c*128; s < c*128 + 128; ++s)
                run += post[(size_t)idx_s[s]*50 + d];
            csum[c][d] = run;
        }
        __syncthreads();
        if (d < 50) {
            float run = 0.f;
            for (int cc = 0; cc < c; ++cc) run += csum[cc][d];
            for (int s = c*128; s < c*128 + 128; ++s) {
                run += post[(size_t)idx_s[s]*50 + d];
                pref[(size_t)s*64 + d] = run;
            }
        }
    } else {                              // ---- emb fp32 -> bf16 padded rows
        if (!do_emb) return;
        unsigned short* embb = ws + OFF_EMBB/2;
        const int blk = bid - 153;                   // 0..255
        const int r0  = blk * 196;
        if (r0 >= 50000) return;
        const int nr  = min(196, 50000 - r0);
        const int n   = nr * 56;
        for (int i = tid; i < n; i += 256) {
            int r = i / 56, j = i - r*56;
            float v = (j < 50) ? emb[(size_t)(r0 + r)*50 + j] : 0.f;
            embb[(size_t)(r0 + r)*56 + j] = f2bf(v);
        }
    }
}

// ---------------- MFMA helpers (verified in rounds 2-3) ----------------------
__device__ __forceinline__ void load_afrags(bf16x8 (&a)[16],
    const unsigned short* h, int row, int kq)
{
#pragma unroll
    for (int ks = 0; ks < 16; ++ks)
        a[ks] = *(const bf16x8*)((const char*)h +
                  (((unsigned)(row * 1024 + ks * 64 + kq * 16)) ^ ((row & 7) << 4)));
}

template<int KS>
__device__ __forceinline__ void layer_compute(
    const bf16x8 (&a)[KS], const unsigned short* __restrict__ Wt,
    const float* __restrict__ bias, unsigned short* hout,
    int wave, int row, int kq)
{
#pragma unroll
    for (int nt = 0; nt < 4; nt += 2) {
        const int c0 = wave * 64 + nt * 16 + row;
        const int c1 = c0 + 16;
        const unsigned short* p0 = Wt + (size_t)c0 * (KS * 32) + kq * 8;
        const unsigned short* p1 = Wt + (size_t)c1 * (KS * 32) + kq * 8;
        bf16x8 bv0[KS], bv1[KS];
#pragma unroll
        for (int ks = 0; ks < KS; ++ks) {           // all B loads issued first (ILP)
            bv0[ks] = *(const bf16x8*)(p0 + ks * 32);
            bv1[ks] = *(const bf16x8*)(p1 + ks * 32);
        }
        f32x4 acc0 = {0.f, 0.f, 0.f, 0.f};
        f32x4 acc1 = {0.f, 0.f, 0.f, 0.f};
#pragma unroll
        for (int ks = 0; ks < KS; ++ks) {
            acc0 = MFMA16(a[ks], bv0[ks], acc0);
            acc1 = MFMA16(a[ks], bv1[ks], acc1);
        }
        const float bb0 = bias[c0], bb1 = bias[c1];
#pragma unroll
        for (int r = 0; r < 4; ++r) {
            int hrow = kq * 4 + r;
            unsigned base = hrow * 1024;
            *(unsigned short*)((char*)hout + ((base + c0 * 2) ^ ((hrow & 7) << 4))) =
                f2bf(fmaxf(acc0[r] + bb0, 0.f));
            *(unsigned short*)((char*)hout + ((base + c1 * 2) ^ ((hrow & 7) << 4))) =
                f2bf(fmaxf(acc1[r] + bb1, 0.f));
        }
    }
}

// ---------------- dan_fused: pooling + 4-layer MFMA MLP ----------------------
// 256 blocks x 512 threads (1/CU). Wave w pools batch row b0+w (per-lane token
// streaming, 7x dwordx4 per token from padded bf16 table), 2-step shfl_xor +
// LDS reduce, then 8 waves run the M=16(8 real)-row MLP with LDS ping-pong.
template<int EMODE>     // 0 = padded bf16 table in ws, 1 = fallback fp32 float2
__global__ __launch_bounds__(512) void dan_fused(
    const float* __restrict__ emb, const int* __restrict__ seq,
    const int* __restrict__ seqlen, const unsigned short* __restrict__ ws_ro,
    const float* __restrict__ pref,
    const float* __restrict__ b1, const float* __restrict__ b2,
    const float* __restrict__ b3, const float* __restrict__ bfin,
    float* __restrict__ out)
{
    __shared__ float          poolred[8][16][52];   // 26.6 KB
    __shared__ unsigned short pooled_s[16][144];    // 4.6 KB, pitch 144 (16B-aligned, 4-way banks)
    __shared__ unsigned short hA[8192];             // 16 KB
    __shared__ unsigned short hB[8192];             // 16 KB
    __shared__ int Ls[8];

    const int tid  = threadIdx.x;
    const int wave = tid >> 6;
    const int lane = tid & 63;
    const int row  = lane & 15;
    const int kq   = lane >> 4;
    const int b0   = blockIdx.x * 8;

    const unsigned short* Wt1 = ws_ro + OFF_WT1 / 2;
    const unsigned short* Wt2 = ws_ro + OFF_WT2 / 2;
    const unsigned short* Wt3 = ws_ro + OFF_WT3 / 2;
    const unsigned short* Wtf = ws_ro + OFF_WTF / 2;

    // W1 fragments preloaded (independent of pooling -> issues early)
    bf16x8 w1f[4][4];
#pragma unroll
    for (int ci = 0; ci < 4; ++ci) {
        const unsigned short* p = Wt1 + (size_t)(wave*64 + ci*16 + row) * 128 + kq*8;
#pragma unroll
        for (int ks = 0; ks < 4; ++ks) w1f[ci][ks] = *(const bf16x8*)(p + ks * 32);
    }

    // ---- pooling: wave w owns batch row b0+w; lane streams tokens lane+64k
    const int b = b0 + wave;
    const int L = seqlen[b];
    if (lane == 0) Ls[wave] = L;
    const int* seqrow = seq + (size_t)b * S_;

    float acc[56];
#pragma unroll
    for (int d = 0; d < 56; ++d) acc[d] = 0.f;

    if (EMODE == 0) {
        const uint4* tbl = (const uint4*)(ws_ro + OFF_EMBB / 2);
        for (int s = lane; s < L; s += 64) {
            const int tok = seqrow[s];
            const uint4* rp = tbl + (size_t)tok * 7;
            uint4 q[7];
#pragma unroll
            for (int t = 0; t < 7; ++t) q[t] = rp[t];    // 7 dwordx4 in flight
#pragma unroll
            for (int t = 0; t < 7; ++t) {
                unsigned dw[4] = {q[t].x, q[t].y, q[t].z, q[t].w};
#pragma unroll
                for (int u = 0; u < 4; ++u) {
                    acc[t*8 + 2*u]     += __uint_as_float(dw[u] << 16);
                    acc[t*8 + 2*u + 1] += __uint_as_float(dw[u] & 0xffff0000u);
                }
            }
        }
    } else {
        for (int s = lane; s < L; s += 64) {
            const int tok = seqrow[s];
            const float2* rp = (const float2*)(emb + (size_t)tok * 50);
            float2 v[25];
#pragma unroll
            for (int i = 0; i < 25; ++i) v[i] = rp[i];
#pragma unroll
            for (int i = 0; i < 25; ++i) { acc[2*i] += v[i].x; acc[2*i+1] += v[i].y; }
        }
    }

#pragma unroll
    for (int d = 0; d < 50; ++d) acc[d] += __shfl_xor(acc[d], 32);
#pragma unroll
    for (int d = 0; d < 50; ++d) acc[d] += __shfl_xor(acc[d], 16);
    if (lane < 16) {
#pragma unroll
        for (int d = 0; d < 50; ++d) poolred[wave][lane][d] = acc[d];
    }
    __syncthreads();

    // ---- build pooled_s bf16 [16][144] (rows 8..15 zero)
    for (int i = tid; i < 16 * 144; i += 512) {
        int r = i / 144, k = i - r * 144;
        float v = 0.f;
        if (r < 8) {
            float Lr = (float)Ls[r];
            if (k < 50) {
                float sum = 0.f;
#pragma unroll
                for (int j = 0; j < 16; ++j) sum += poolred[r][j][k];
                v = sum / Lr;
            } else if (k < 100) {
                v = pref[(size_t)(Ls[r] - 1) * 64 + (k - 50)] / Lr;
            }
        }
        ((unsigned short*)pooled_s)[i] = f2bf(v);
    }
    __syncthreads();

    // ---- Layer 1 (K=128) from pooled_s, weights already in regs
    bf16x8 a1[4];
#pragma unroll
    for (int ks = 0; ks < 4; ++ks)
        a1[ks] = *(const bf16x8*)&pooled_s[row][ks*32 + kq*8];
#pragma unroll
    for (int ci = 0; ci < 4; ++ci) {
        const int c = wave*64 + ci*16 + row;
        f32x4 a0 = {0.f, 0.f, 0.f, 0.f};
#pragma unroll
        for (int ks = 0; ks < 4; ++ks) a0 = MFMA16(a1[ks], w1f[ci][ks], a0);
        const float bb = b1[c];
#pragma unroll
        for (int r4 = 0; r4 < 4; ++r4) {
            int hrow = kq*4 + r4;
            unsigned bofs = hrow * 1024;
            *(unsigned short*)((char*)hA + ((bofs + c*2) ^ ((hrow & 7) << 4))) =
                f2bf(fmaxf(a0[r4] + bb, 0.f));
        }
    }
    __syncthreads();

    // ---- Layer 2 (K=512): hA -> hB
    bf16x8 a[16];
    load_afrags(a, hA, row, kq);
    layer_compute<16>(a, Wt2, b2, hB, wave, row, kq);
    __syncthreads();

    // ---- Layer 3 (K=512): hB -> hA
    load_afrags(a, hB, row, kq);
    layer_compute<16>(a, Wt3, b3, hA, wave, row, kq);
    __syncthreads();

    // ---- Final (K=512, N padded 2->16): wave 0 only
    if (wave == 0) {
        load_afrags(a, hA, row, kq);
        f32x4 accf = {0.f, 0.f, 0.f, 0.f};
        const unsigned short* pw = Wtf + (size_t)row * 512 + kq * 8;
#pragma unroll
        for (int ks = 0; ks < 16; ++ks) {
            bf16x8 bv = *(const bf16x8*)(pw + ks * 32);
            accf = MFMA16(a[ks], bv, accf);
        }
        if (row < 2 && kq < 2) {
            float bb = bfin[row];
#pragma unroll
            for (int r4 = 0; r4 < 4; ++r4) {
                int m = kq*4 + r4;                   // real rows 0..7
                out[(size_t)(b0 + m) * 2 + row] = accf[r4] + bb;
            }
        }
    }
}

extern "C" void kernel_launch(void* const* d_in, const int* in_sizes, int n_in,
                              void* d_out, int out_size, void* d_ws, size_t ws_size,
                              hipStream_t stream)
{
    const float* emb    = (const float*)d_in[0];
    const float* post   = (const float*)d_in[1];
    const float* W1     = (const float*)d_in[2];
    const float* b1     = (const float*)d_in[3];
    const float* W2     = (const float*)d_in[4];
    const float* b2     = (const float*)d_in[5];
    const float* W3     = (const float*)d_in[6];
    const float* b3     = (const float*)d_in[7];
    const float* Wf     = (const float*)d_in[8];
    const float* bf     = (const float*)d_in[9];
    const int*   seq    = (const int*)d_in[10];
    const int*   seqlen = (const int*)d_in[11];
    const int*   pos    = (const int*)d_in[12];
    float*       out    = (float*)d_out;

    unsigned short* ws = (unsigned short*)d_ws;
    float* pref = (float*)((char*)d_ws + OFF_PREF);
    const int do_emb = (ws_size >= (size_t)WS_NEED_PAD) ? 1 : 0;

    prep_convert<<<409, 256, 0, stream>>>(W1, W2, W3, Wf, post, pos, emb,
                                          ws, pref, do_emb);
    if (do_emb)
        dan_fused<0><<<B_ / 8, 512, 0, stream>>>(emb, seq, seqlen, ws, pref,
                                                 b1, b2, b3, bf, out);
    else
        dan_fused<1><<<B_ / 8, 512, 0, stream>>>(emb, seq, seqlen, ws, pref,
                                                 b1, b2, b3, bf, out);
}